// Round 1
// baseline (240.104 us; speedup 1.0000x reference)
//
#include <hip/hip_runtime.h>
#include <hip/hip_bf16.h>

// ---------- types ----------
typedef __attribute__((ext_vector_type(4))) float  f32x4;
typedef __attribute__((ext_vector_type(8))) short  bf16x8;   // 8 bf16 in 4 VGPRs
typedef __attribute__((ext_vector_type(8))) unsigned short u16x8;

__device__ __forceinline__ unsigned short f2bf(float f) {
    union { float f; unsigned u; } v; v.f = f;
    unsigned u = v.u;
    unsigned r = u + 0x7fffu + ((u >> 16) & 1u);   // round-to-nearest-even
    return (unsigned short)(r >> 16);
}

// ---------- problem constants ----------
// B=2, T=64, CH=512, Hs=24, Ws=24, HW=576, P=1152, DIM=256, HEADS=8, HD=32
// M = 73728 rows, ordered m = t*1152 + p, p = b*576 + hw  (hw = h*24+w)

// ---------- K0: weights fp32 -> bf16 ----------
__global__ void cvt_weights(const float* __restrict__ qkv_w, const float* __restrict__ proj_w,
                            unsigned short* __restrict__ wq, unsigned short* __restrict__ wp) {
    int i = blockIdx.x * 256 + threadIdx.x;          // 262144 total
    if (i < 196608) wq[i] = f2bf(qkv_w[i]);
    else            wp[i - 196608] = f2bf(proj_w[i - 196608]);
}

// ---------- K1: copy a-half (identical flat offsets within each (b,t) slab) ----------
__global__ void copy_a(const float* __restrict__ x, float* __restrict__ out) {
    long long i = (long long)blockIdx.x * 256 + threadIdx.x;   // float4 index, 4718592 total
    int chunk = (int)(i / 36864);            // (b*64+t), 128 slabs
    int r     = (int)(i % 36864);            // within first 256*576/4 float4s
    size_t off = (size_t)chunk * 73728 + r;  // slab stride 512*576/4
    ((float4*)out)[off] = ((const float4*)x)[off];
}

// ---------- K2: transpose b-half -> xb[m][256] bf16 ----------
__global__ __launch_bounds__(256) void transpose_b(const float* __restrict__ x,
                                                   unsigned short* __restrict__ xb) {
    __shared__ unsigned short tile[256][72];          // [c][hw], padded
    const int bt  = blockIdx.x;                       // b*64+t, 0..127
    const int hw0 = blockIdx.y * 64;                  // 0..512 step 64 (9 tiles)
    const int tid = threadIdx.x;
    const float* src = x + ((size_t)bt * 512 + 256) * 576 + hw0;
    const int c_sub = tid >> 4, l16 = tid & 15;
    #pragma unroll
    for (int it = 0; it < 16; ++it) {
        int cc = it * 16 + c_sub;
        const float4 v = *(const float4*)(src + (size_t)cc * 576 + l16 * 4);
        tile[cc][l16 * 4 + 0] = f2bf(v.x);
        tile[cc][l16 * 4 + 1] = f2bf(v.y);
        tile[cc][l16 * 4 + 2] = f2bf(v.z);
        tile[cc][l16 * 4 + 3] = f2bf(v.w);
    }
    __syncthreads();
    const int row = tid >> 2;                 // hw within tile
    const int cs  = (tid & 3) * 64;           // c segment
    const int b = bt >> 6, t = bt & 63;
    size_t m = (size_t)t * 1152 + (size_t)b * 576 + hw0 + row;
    unsigned short* dst = xb + m * 256 + cs;
    #pragma unroll
    for (int q = 0; q < 8; ++q) {
        u16x8 v;
        #pragma unroll
        for (int u = 0; u < 8; ++u) v[u] = tile[cs + q * 8 + u][row];
        *(u16x8*)(dst + q * 8) = v;
    }
}

// ---------- K3: QKV GEMM  (M=73728, N=768, K=256), A,Wt both K-contiguous ----------
__global__ __launch_bounds__(256) void gemm_qkv(const unsigned short* __restrict__ A,
                                                const unsigned short* __restrict__ Wt,
                                                const float* __restrict__ bias,
                                                unsigned short* __restrict__ out) {
    __shared__ unsigned short As[128][72];   // 64 bf16 data + 16B pad
    __shared__ unsigned short Bs[128][72];
    const int m0 = blockIdx.x * 128, n0 = blockIdx.y * 128;
    const int tid = threadIdx.x;
    const int lane = tid & 63, wid = tid >> 6;
    const int wy = wid >> 1, wx = wid & 1;
    const int c = lane & 15, g = lane >> 4;
    const int srow = tid >> 3, skc = (tid & 7) * 8;
    f32x4 acc[4][4] = {};
    for (int k0 = 0; k0 < 256; k0 += 64) {
        #pragma unroll
        for (int i = 0; i < 4; ++i) {
            int row = srow + 32 * i;
            u16x8 va = *(const u16x8*)(A  + (size_t)(m0 + row) * 256 + k0 + skc);
            *(u16x8*)(&As[row][skc]) = va;
            u16x8 vb = *(const u16x8*)(Wt + (size_t)(n0 + row) * 256 + k0 + skc);
            *(u16x8*)(&Bs[row][skc]) = vb;
        }
        __syncthreads();
        #pragma unroll
        for (int kk = 0; kk < 2; ++kk) {
            bf16x8 af[4], bfg[4];
            #pragma unroll
            for (int mt = 0; mt < 4; ++mt)
                af[mt] = *(const bf16x8*)(&As[wy * 64 + mt * 16 + c][kk * 32 + g * 8]);
            #pragma unroll
            for (int nt = 0; nt < 4; ++nt)
                bfg[nt] = *(const bf16x8*)(&Bs[wx * 64 + nt * 16 + c][kk * 32 + g * 8]);
            #pragma unroll
            for (int mt = 0; mt < 4; ++mt)
                #pragma unroll
                for (int nt = 0; nt < 4; ++nt)
                    acc[mt][nt] = __builtin_amdgcn_mfma_f32_16x16x32_bf16(af[mt], bfg[nt], acc[mt][nt], 0, 0, 0);
        }
        __syncthreads();
    }
    #pragma unroll
    for (int nt = 0; nt < 4; ++nt) {
        int col = n0 + wx * 64 + nt * 16 + c;
        float bv = bias[col];
        #pragma unroll
        for (int mt = 0; mt < 4; ++mt) {
            int row = m0 + wy * 64 + mt * 16 + g * 4;
            #pragma unroll
            for (int r = 0; r < 4; ++r)
                out[(size_t)(row + r) * 768 + col] = f2bf(acc[mt][nt][r] + bv);
        }
    }
}

// ---------- K4: attention per (p, head); 1 wave ----------
__global__ __launch_bounds__(64) void attn_kernel(const unsigned short* __restrict__ qkv,
                                                  const float* __restrict__ rpb,
                                                  unsigned short* __restrict__ att) {
    __shared__ float bias_s[127];
    __shared__ unsigned short vT[32][72];   // [d][j], padded
    __shared__ unsigned short P[64][72];    // [i][j], padded
    const int blk = blockIdx.x;
    const int p = blk >> 3, h = blk & 7;
    const int lane = threadIdx.x;
    const int c = lane & 15, g = lane >> 4;

    bias_s[lane] = rpb[lane * 8 + h];
    if (lane < 63) bias_s[64 + lane] = rpb[(64 + lane) * 8 + h];

    {   // load V rows (lane = j) and transpose into vT[d][j]
        const unsigned short* vrow = qkv + (size_t)(lane * 1152 + p) * 768 + 512 + h * 32;
        #pragma unroll
        for (int q = 0; q < 4; ++q) {
            u16x8 v = *(const u16x8*)(vrow + q * 8);
            #pragma unroll
            for (int u = 0; u < 8; ++u) vT[q * 8 + u][lane] = v[u];
        }
    }
    // Q/K fragments straight from global (L2-hot)
    bf16x8 qf[4], kf[4];
    #pragma unroll
    for (int mt = 0; mt < 4; ++mt)
        qf[mt] = *(const bf16x8*)(qkv + (size_t)((mt * 16 + c) * 1152 + p) * 768 + h * 32 + g * 8);
    #pragma unroll
    for (int nt = 0; nt < 4; ++nt)
        kf[nt] = *(const bf16x8*)(qkv + (size_t)((nt * 16 + c) * 1152 + p) * 768 + 256 + h * 32 + g * 8);
    f32x4 s[4][4] = {};
    #pragma unroll
    for (int mt = 0; mt < 4; ++mt)
        #pragma unroll
        for (int nt = 0; nt < 4; ++nt)
            s[mt][nt] = __builtin_amdgcn_mfma_f32_16x16x32_bf16(qf[mt], kf[nt], s[mt][nt], 0, 0, 0);
    __syncthreads();   // bias_s + vT visible

    const float scale = 0.17677669529663687f;  // 1/sqrt(32)
    #pragma unroll
    for (int mt = 0; mt < 4; ++mt) {
        #pragma unroll
        for (int r = 0; r < 4; ++r) {
            int i = mt * 16 + g * 4 + r;
            float vals[4];
            #pragma unroll
            for (int nt = 0; nt < 4; ++nt) {
                int j = nt * 16 + c;
                float v = s[mt][nt][r] * scale + bias_s[j - i + 63];
                vals[nt] = (j > i) ? -1e30f : v;
            }
            float mx = fmaxf(fmaxf(vals[0], vals[1]), fmaxf(vals[2], vals[3]));
            #pragma unroll
            for (int off = 1; off < 16; off <<= 1) mx = fmaxf(mx, __shfl_xor(mx, off, 64));
            float sum = 0.f;
            #pragma unroll
            for (int nt = 0; nt < 4; ++nt) { vals[nt] = __expf(vals[nt] - mx); sum += vals[nt]; }
            #pragma unroll
            for (int off = 1; off < 16; off <<= 1) sum += __shfl_xor(sum, off, 64);
            float inv = 1.0f / sum;
            #pragma unroll
            for (int nt = 0; nt < 4; ++nt) P[i][nt * 16 + c] = f2bf(vals[nt] * inv);
        }
    }
    __syncthreads();

    f32x4 o[4][2] = {};
    #pragma unroll
    for (int kk = 0; kk < 2; ++kk) {
        bf16x8 pa[4], vb[2];
        #pragma unroll
        for (int mt = 0; mt < 4; ++mt)
            pa[mt] = *(const bf16x8*)(&P[mt * 16 + c][kk * 32 + g * 8]);
        #pragma unroll
        for (int nt = 0; nt < 2; ++nt)
            vb[nt] = *(const bf16x8*)(&vT[nt * 16 + c][kk * 32 + g * 8]);
        #pragma unroll
        for (int mt = 0; mt < 4; ++mt)
            #pragma unroll
            for (int nt = 0; nt < 2; ++nt)
                o[mt][nt] = __builtin_amdgcn_mfma_f32_16x16x32_bf16(pa[mt], vb[nt], o[mt][nt], 0, 0, 0);
    }
    #pragma unroll
    for (int mt = 0; mt < 4; ++mt)
        #pragma unroll
        for (int nt = 0; nt < 2; ++nt) {
            int d = nt * 16 + c;
            #pragma unroll
            for (int r = 0; r < 4; ++r) {
                int i = mt * 16 + g * 4 + r;
                att[(size_t)(i * 1152 + p) * 256 + h * 32 + d] = f2bf(o[mt][nt][r]);
            }
        }
}

// ---------- K5: proj GEMM (M=73728, N=256, K=256) + scatter to output ----------
__global__ __launch_bounds__(256) void gemm_proj(const unsigned short* __restrict__ A,
                                                 const unsigned short* __restrict__ Wt,
                                                 const float* __restrict__ bias,
                                                 float* __restrict__ out) {
    __shared__ unsigned short As[128][72];
    __shared__ unsigned short Bs[128][72];
    const int m0 = blockIdx.x * 128, n0 = blockIdx.y * 128;
    const int tid = threadIdx.x;
    const int lane = tid & 63, wid = tid >> 6;
    const int wy = wid >> 1, wx = wid & 1;
    const int c = lane & 15, g = lane >> 4;
    const int srow = tid >> 3, skc = (tid & 7) * 8;
    f32x4 acc[4][4] = {};
    for (int k0 = 0; k0 < 256; k0 += 64) {
        #pragma unroll
        for (int i = 0; i < 4; ++i) {
            int row = srow + 32 * i;
            u16x8 va = *(const u16x8*)(A  + (size_t)(m0 + row) * 256 + k0 + skc);
            *(u16x8*)(&As[row][skc]) = va;
            u16x8 vb = *(const u16x8*)(Wt + (size_t)(n0 + row) * 256 + k0 + skc);
            *(u16x8*)(&Bs[row][skc]) = vb;
        }
        __syncthreads();
        #pragma unroll
        for (int kk = 0; kk < 2; ++kk) {
            bf16x8 af[4], bfg[4];
            #pragma unroll
            for (int mt = 0; mt < 4; ++mt)
                af[mt] = *(const bf16x8*)(&As[wy * 64 + mt * 16 + c][kk * 32 + g * 8]);
            #pragma unroll
            for (int nt = 0; nt < 4; ++nt)
                bfg[nt] = *(const bf16x8*)(&Bs[wx * 64 + nt * 16 + c][kk * 32 + g * 8]);
            #pragma unroll
            for (int mt = 0; mt < 4; ++mt)
                #pragma unroll
                for (int nt = 0; nt < 4; ++nt)
                    acc[mt][nt] = __builtin_amdgcn_mfma_f32_16x16x32_bf16(af[mt], bfg[nt], acc[mt][nt], 0, 0, 0);
        }
        __syncthreads();
    }
    // epilogue: m = t*1152 + b*576 + hw; quad of rows = contiguous hw -> float4 store
    #pragma unroll
    for (int nt = 0; nt < 4; ++nt) {
        int col = n0 + wx * 64 + nt * 16 + c;   // 0..255
        float bv = bias[col];
        #pragma unroll
        for (int mt = 0; mt < 4; ++mt) {
            int mbase = m0 + wy * 64 + mt * 16 + g * 4;     // multiple of 4
            int t   = mbase / 1152;
            int rem = mbase % 1152;
            int b   = rem / 576;
            int hw  = rem % 576;
            float4 v;
            v.x = acc[mt][nt][0] + bv;
            v.y = acc[mt][nt][1] + bv;
            v.z = acc[mt][nt][2] + bv;
            v.w = acc[mt][nt][3] + bv;
            float* dst = out + ((size_t)(b * 64 + t) * 512 + 256 + col) * 576 + hw;
            *(float4*)dst = v;
        }
    }
}

// ---------- launcher ----------
extern "C" void kernel_launch(void* const* d_in, const int* in_sizes, int n_in,
                              void* d_out, int out_size, void* d_ws, size_t ws_size,
                              hipStream_t stream) {
    (void)in_sizes; (void)n_in; (void)out_size;
    const float* x      = (const float*)d_in[0];
    const float* rpb    = (const float*)d_in[1];
    const float* qkv_w  = (const float*)d_in[2];
    const float* qkv_b  = (const float*)d_in[3];
    const float* proj_w = (const float*)d_in[4];
    const float* proj_b = (const float*)d_in[5];
    float* out = (float*)d_out;

    // workspace layout (bytes): wq 393216 | wp 131072 | xb 37748736 | qkv 113246208
    char* ws = (char*)d_ws;
    unsigned short* wq  = (unsigned short*)ws;
    unsigned short* wp  = (unsigned short*)(ws + 393216);
    unsigned short* xb  = (unsigned short*)(ws + 524288);
    unsigned short* qkv = (unsigned short*)(ws + 524288 + 37748736);
    unsigned short* att = xb;    // reuse xb region after gemm_qkv consumed it
    if (ws_size < (size_t)524288 + 37748736 + 113246208) return;  // need ~145 MB

    cvt_weights<<<1024, 256, 0, stream>>>(qkv_w, proj_w, wq, wp);
    copy_a<<<18432, 256, 0, stream>>>(x, out);
    transpose_b<<<dim3(128, 9), 256, 0, stream>>>(x, xb);
    gemm_qkv<<<dim3(576, 6), 256, 0, stream>>>(xb, wq, qkv_b, qkv);
    attn_kernel<<<9216, 64, 0, stream>>>(qkv, rpb, att);
    gemm_proj<<<dim3(576, 2), 256, 0, stream>>>(att, wp, proj_b, out);
}

// Round 2
// 225.781 us; speedup vs baseline: 1.0634x; 1.0634x over previous
//
#include <hip/hip_runtime.h>
#include <hip/hip_bf16.h>

// ---------- types ----------
typedef __attribute__((ext_vector_type(4))) float  f32x4;
typedef __attribute__((ext_vector_type(8))) short  bf16x8;   // 8 bf16 in 4 VGPRs
typedef __attribute__((ext_vector_type(8))) unsigned short u16x8;
typedef __attribute__((ext_vector_type(4))) unsigned short u16x4;

__device__ __forceinline__ unsigned short f2bf(float f) {
    union { float f; unsigned u; } v; v.f = f;
    unsigned u = v.u;
    unsigned r = u + 0x7fffu + ((u >> 16) & 1u);   // round-to-nearest-even
    return (unsigned short)(r >> 16);
}

__device__ __forceinline__ void gload16(const void* g, void* l) {
    __builtin_amdgcn_global_load_lds((const __attribute__((address_space(1))) unsigned*)g,
                                     (__attribute__((address_space(3))) unsigned*)l, 16, 0, 0);
}

// ---------- problem constants ----------
// B=2, T=64, CH=512, Hs=24, Ws=24, HW=576, P=1152, DIM=256, HEADS=8, HD=32
// M = 73728 rows, ordered m = t*1152 + p, p = b*576 + hw

// ---------- K0: weights fp32 -> bf16 ----------
__global__ void cvt_weights(const float* __restrict__ qkv_w, const float* __restrict__ proj_w,
                            unsigned short* __restrict__ wq, unsigned short* __restrict__ wp) {
    int i = blockIdx.x * 256 + threadIdx.x;          // 262144 total
    if (i < 196608) wq[i] = f2bf(qkv_w[i]);
    else            wp[i - 196608] = f2bf(proj_w[i - 196608]);
}

// ---------- K1: copy a-half ----------
__global__ void copy_a(const float* __restrict__ x, float* __restrict__ out) {
    long long i = (long long)blockIdx.x * 256 + threadIdx.x;   // float4 index
    int chunk = (int)(i / 36864);            // (b*64+t), 128 slabs
    int r     = (int)(i % 36864);
    size_t off = (size_t)chunk * 73728 + r;
    ((float4*)out)[off] = ((const float4*)x)[off];
}

// ---------- K2: transpose b-half -> xb[m][256] bf16 ----------
__global__ __launch_bounds__(256) void transpose_b(const float* __restrict__ x,
                                                   unsigned short* __restrict__ xb) {
    __shared__ unsigned short tile[256][72];
    const int bt  = blockIdx.x;
    const int hw0 = blockIdx.y * 64;
    const int tid = threadIdx.x;
    const float* src = x + ((size_t)bt * 512 + 256) * 576 + hw0;
    const int c_sub = tid >> 4, l16 = tid & 15;
    #pragma unroll
    for (int it = 0; it < 16; ++it) {
        int cc = it * 16 + c_sub;
        const float4 v = *(const float4*)(src + (size_t)cc * 576 + l16 * 4);
        tile[cc][l16 * 4 + 0] = f2bf(v.x);
        tile[cc][l16 * 4 + 1] = f2bf(v.y);
        tile[cc][l16 * 4 + 2] = f2bf(v.z);
        tile[cc][l16 * 4 + 3] = f2bf(v.w);
    }
    __syncthreads();
    const int row = tid >> 2;
    const int cs  = (tid & 3) * 64;
    const int b = bt >> 6, t = bt & 63;
    size_t m = (size_t)t * 1152 + (size_t)b * 576 + hw0 + row;
    unsigned short* dst = xb + m * 256 + cs;
    #pragma unroll
    for (int q = 0; q < 8; ++q) {
        u16x8 v;
        #pragma unroll
        for (int u = 0; u < 8; ++u) v[u] = tile[cs + q * 8 + u][row];
        *(u16x8*)(dst + q * 8) = v;
    }
}

// ---------- K3: QKV GEMM (M=73728, N=768, K=256), operands swapped: D[n][m] ----------
// A-operand = weight rows (n), B-operand = xb rows (m). Both K-contiguous.
__global__ __launch_bounds__(256, 4) void gemm_qkv(const unsigned short* __restrict__ A,  // xb
                                                   const unsigned short* __restrict__ Wt, // weights
                                                   const float* __restrict__ bias,
                                                   unsigned short* __restrict__ out) {
    __shared__ unsigned short Ws[128 * 64];   // [n-row][64 k-shorts], XOR-swizzled content
    __shared__ unsigned short Xs[128 * 64];   // [m-row][64 k-shorts]
    const int m0 = blockIdx.x * 128, n0 = blockIdx.y * 128;
    const int tid = threadIdx.x;
    const int lane = tid & 63, w = tid >> 6;
    const int wy = w >> 1, wx = w & 1;        // wave: 64 n-rows x 64 m-cols
    const int c = lane & 15, g = lane >> 4;
    const int lr = lane >> 3, lu = lane & 7;  // staging: row-in-issue, 16B unit
    const int su = lu ^ lr;                   // pre-swizzled source unit (involution)
    const int cs7 = c & 7;
    f32x4 acc[4][4] = {};
    for (int k0 = 0; k0 < 256; k0 += 64) {
        #pragma unroll
        for (int q = 0; q < 4; ++q) {
            int R = w * 32 + q * 8;
            gload16(Wt + (size_t)(n0 + R + lr) * 256 + k0 + su * 8, &Ws[R * 64]);
            gload16(A  + (size_t)(m0 + R + lr) * 256 + k0 + su * 8, &Xs[R * 64]);
        }
        __syncthreads();
        #pragma unroll
        for (int kk = 0; kk < 2; ++kk) {
            bf16x8 af[4], bx[4];
            #pragma unroll
            for (int a2 = 0; a2 < 4; ++a2)
                af[a2] = *(const bf16x8*)(&Ws[(wy * 64 + a2 * 16 + c) * 64 + (((kk * 4 + g) ^ cs7) * 8)]);
            #pragma unroll
            for (int b2 = 0; b2 < 4; ++b2)
                bx[b2] = *(const bf16x8*)(&Xs[(wx * 64 + b2 * 16 + c) * 64 + (((kk * 4 + g) ^ cs7) * 8)]);
            #pragma unroll
            for (int a2 = 0; a2 < 4; ++a2)
                #pragma unroll
                for (int b2 = 0; b2 < 4; ++b2)
                    acc[a2][b2] = __builtin_amdgcn_mfma_f32_16x16x32_bf16(af[a2], bx[b2], acc[a2][b2], 0, 0, 0);
        }
        __syncthreads();
    }
    #pragma unroll
    for (int a2 = 0; a2 < 4; ++a2) {
        int n = n0 + wy * 64 + a2 * 16 + g * 4;
        float4 bv = *(const float4*)(bias + n);
        #pragma unroll
        for (int b2 = 0; b2 < 4; ++b2) {
            int m = m0 + wx * 64 + b2 * 16 + c;
            u16x4 v;
            v[0] = f2bf(acc[a2][b2][0] + bv.x);
            v[1] = f2bf(acc[a2][b2][1] + bv.y);
            v[2] = f2bf(acc[a2][b2][2] + bv.z);
            v[3] = f2bf(acc[a2][b2][3] + bv.w);
            *(u16x4*)(out + (size_t)m * 768 + n) = v;
        }
    }
}

// ---------- K4: attention per (p, head); 1 wave ----------
__global__ __launch_bounds__(64) void attn_kernel(const unsigned short* __restrict__ qkv,
                                                  const float* __restrict__ rpb,
                                                  unsigned short* __restrict__ att) {
    __shared__ float bias_s[127];
    __shared__ unsigned short vT[32][72];
    __shared__ unsigned short P[64][72];
    const int blk = blockIdx.x;
    const int p = blk >> 3, h = blk & 7;
    const int lane = threadIdx.x;
    const int c = lane & 15, g = lane >> 4;

    bias_s[lane] = rpb[lane * 8 + h];
    if (lane < 63) bias_s[64 + lane] = rpb[(64 + lane) * 8 + h];

    {
        const unsigned short* vrow = qkv + (size_t)(lane * 1152 + p) * 768 + 512 + h * 32;
        #pragma unroll
        for (int q = 0; q < 4; ++q) {
            u16x8 v = *(const u16x8*)(vrow + q * 8);
            #pragma unroll
            for (int u = 0; u < 8; ++u) vT[q * 8 + u][lane] = v[u];
        }
    }
    bf16x8 qf[4], kf[4];
    #pragma unroll
    for (int mt = 0; mt < 4; ++mt)
        qf[mt] = *(const bf16x8*)(qkv + (size_t)((mt * 16 + c) * 1152 + p) * 768 + h * 32 + g * 8);
    #pragma unroll
    for (int nt = 0; nt < 4; ++nt)
        kf[nt] = *(const bf16x8*)(qkv + (size_t)((nt * 16 + c) * 1152 + p) * 768 + 256 + h * 32 + g * 8);
    f32x4 s[4][4] = {};
    #pragma unroll
    for (int mt = 0; mt < 4; ++mt)
        #pragma unroll
        for (int nt = 0; nt < 4; ++nt)
            s[mt][nt] = __builtin_amdgcn_mfma_f32_16x16x32_bf16(qf[mt], kf[nt], s[mt][nt], 0, 0, 0);
    __syncthreads();

    const float scale = 0.17677669529663687f;  // 1/sqrt(32)
    #pragma unroll
    for (int mt = 0; mt < 4; ++mt) {
        #pragma unroll
        for (int r = 0; r < 4; ++r) {
            int i = mt * 16 + g * 4 + r;
            float vals[4];
            #pragma unroll
            for (int nt = 0; nt < 4; ++nt) {
                int j = nt * 16 + c;
                float v = s[mt][nt][r] * scale + bias_s[j - i + 63];
                vals[nt] = (j > i) ? -1e30f : v;
            }
            float mx = fmaxf(fmaxf(vals[0], vals[1]), fmaxf(vals[2], vals[3]));
            #pragma unroll
            for (int off = 1; off < 16; off <<= 1) mx = fmaxf(mx, __shfl_xor(mx, off, 64));
            float sum = 0.f;
            #pragma unroll
            for (int nt = 0; nt < 4; ++nt) { vals[nt] = __expf(vals[nt] - mx); sum += vals[nt]; }
            #pragma unroll
            for (int off = 1; off < 16; off <<= 1) sum += __shfl_xor(sum, off, 64);
            float inv = 1.0f / sum;
            #pragma unroll
            for (int nt = 0; nt < 4; ++nt) P[i][nt * 16 + c] = f2bf(vals[nt] * inv);
        }
    }
    __syncthreads();

    f32x4 o[4][2] = {};
    #pragma unroll
    for (int kk = 0; kk < 2; ++kk) {
        bf16x8 pa[4], vb[2];
        #pragma unroll
        for (int mt = 0; mt < 4; ++mt)
            pa[mt] = *(const bf16x8*)(&P[mt * 16 + c][kk * 32 + g * 8]);
        #pragma unroll
        for (int nt = 0; nt < 2; ++nt)
            vb[nt] = *(const bf16x8*)(&vT[nt * 16 + c][kk * 32 + g * 8]);
        #pragma unroll
        for (int mt = 0; mt < 4; ++mt)
            #pragma unroll
            for (int nt = 0; nt < 2; ++nt)
                o[mt][nt] = __builtin_amdgcn_mfma_f32_16x16x32_bf16(pa[mt], vb[nt], o[mt][nt], 0, 0, 0);
    }
    #pragma unroll
    for (int mt = 0; mt < 4; ++mt)
        #pragma unroll
        for (int nt = 0; nt < 2; ++nt) {
            int d = nt * 16 + c;
            #pragma unroll
            for (int r = 0; r < 4; ++r) {
                int i = mt * 16 + g * 4 + r;
                att[(size_t)(i * 1152 + p) * 256 + h * 32 + d] = f2bf(o[mt][nt][r]);
            }
        }
}

// ---------- K5: proj GEMM (M=73728, N=256, K=256) + scatter to output ----------
__global__ __launch_bounds__(256, 4) void gemm_proj(const unsigned short* __restrict__ A,   // att
                                                    const unsigned short* __restrict__ Wt,  // proj w
                                                    const float* __restrict__ bias,
                                                    float* __restrict__ out) {
    __shared__ unsigned short Ws[128 * 64];
    __shared__ unsigned short Xs[128 * 64];
    const int m0 = blockIdx.x * 128, n0 = blockIdx.y * 128;
    const int tid = threadIdx.x;
    const int lane = tid & 63, w = tid >> 6;
    const int wy = w >> 1, wx = w & 1;
    const int c = lane & 15, g = lane >> 4;
    const int lr = lane >> 3, lu = lane & 7;
    const int su = lu ^ lr;
    const int cs7 = c & 7;
    f32x4 acc[4][4] = {};
    for (int k0 = 0; k0 < 256; k0 += 64) {
        #pragma unroll
        for (int q = 0; q < 4; ++q) {
            int R = w * 32 + q * 8;
            gload16(Wt + (size_t)(n0 + R + lr) * 256 + k0 + su * 8, &Ws[R * 64]);
            gload16(A  + (size_t)(m0 + R + lr) * 256 + k0 + su * 8, &Xs[R * 64]);
        }
        __syncthreads();
        #pragma unroll
        for (int kk = 0; kk < 2; ++kk) {
            bf16x8 af[4], bx[4];
            #pragma unroll
            for (int a2 = 0; a2 < 4; ++a2)
                af[a2] = *(const bf16x8*)(&Ws[(wy * 64 + a2 * 16 + c) * 64 + (((kk * 4 + g) ^ cs7) * 8)]);
            #pragma unroll
            for (int b2 = 0; b2 < 4; ++b2)
                bx[b2] = *(const bf16x8*)(&Xs[(wx * 64 + b2 * 16 + c) * 64 + (((kk * 4 + g) ^ cs7) * 8)]);
            #pragma unroll
            for (int a2 = 0; a2 < 4; ++a2)
                #pragma unroll
                for (int b2 = 0; b2 < 4; ++b2)
                    acc[a2][b2] = __builtin_amdgcn_mfma_f32_16x16x32_bf16(af[a2], bx[b2], acc[a2][b2], 0, 0, 0);
        }
        __syncthreads();
    }
    // epilogue: D[n][m], m = t*1152 + b*576 + hw; 16 lanes (c) -> consecutive hw floats
    #pragma unroll
    for (int a2 = 0; a2 < 4; ++a2) {
        int n = n0 + wy * 64 + a2 * 16 + g * 4;
        float4 bv = *(const float4*)(bias + n);
        #pragma unroll
        for (int b2 = 0; b2 < 4; ++b2) {
            int m = m0 + wx * 64 + b2 * 16 + c;
            int t   = m / 1152;
            int rem = m % 1152;
            int bb  = rem / 576;
            int hw  = rem % 576;
            float* dst = out + ((size_t)(bb * 64 + t) * 512 + 256 + n) * 576 + hw;
            dst[0]        = acc[a2][b2][0] + bv.x;
            dst[576]      = acc[a2][b2][1] + bv.y;
            dst[2 * 576]  = acc[a2][b2][2] + bv.z;
            dst[3 * 576]  = acc[a2][b2][3] + bv.w;
        }
    }
}

// ---------- launcher ----------
extern "C" void kernel_launch(void* const* d_in, const int* in_sizes, int n_in,
                              void* d_out, int out_size, void* d_ws, size_t ws_size,
                              hipStream_t stream) {
    (void)in_sizes; (void)n_in; (void)out_size;
    const float* x      = (const float*)d_in[0];
    const float* rpb    = (const float*)d_in[1];
    const float* qkv_w  = (const float*)d_in[2];
    const float* qkv_b  = (const float*)d_in[3];
    const float* proj_w = (const float*)d_in[4];
    const float* proj_b = (const float*)d_in[5];
    float* out = (float*)d_out;

    char* ws = (char*)d_ws;
    unsigned short* wq  = (unsigned short*)ws;
    unsigned short* wp  = (unsigned short*)(ws + 393216);
    unsigned short* xb  = (unsigned short*)(ws + 524288);
    unsigned short* qkv = (unsigned short*)(ws + 524288 + 37748736);
    unsigned short* att = xb;    // reuse xb region after gemm_qkv consumed it
    if (ws_size < (size_t)524288 + 37748736 + 113246208) return;

    cvt_weights<<<1024, 256, 0, stream>>>(qkv_w, proj_w, wq, wp);
    copy_a<<<18432, 256, 0, stream>>>(x, out);
    transpose_b<<<dim3(128, 9), 256, 0, stream>>>(x, xb);
    gemm_qkv<<<dim3(576, 6), 256, 0, stream>>>(xb, wq, qkv_b, qkv);
    attn_kernel<<<9216, 64, 0, stream>>>(qkv, rpb, att);
    gemm_proj<<<dim3(576, 2), 256, 0, stream>>>(att, wp, proj_b, out);
}